// Round 6
// baseline (185.849 us; speedup 1.0000x reference)
//
#include <hip/hip_runtime.h>

// GTConv autoencoder, MI355X — single-kernel (grid-barrier) version.
// Math (verified PASS rounds 2/3/5):
//   S = It(x)Ag + St(x)Bg, Ag = s00 I + s01 Sg, Bg = s10 I + s11 Sg (commute)
//   S^k x[t] = sum_{d,p} c[k][d][p] Sg^p x[t-d] (cyclic);
//   Y[t,m,o] = sum_i sum_{d,p} g[o,i,d,p] Zp[t-d,i,m], g = sum_k h[o,i,k] c[k][d][p]
// Phases (5 grid barriers): P0 prep (SgTp/Sg2Tp/XT/g) -> P1A Zx -> P1B e1+Z(L2)
//   -> P2 e2+Z(L3) -> P3 d1+Z(L4) -> P4 d2 -> out.
// 96 blocks x 384 threads (h=t/192 n-half, m=t%192 node): co-resident (<=256 CUs).
// Grid barrier: block0 ready-gate zeroes cells (robust to any ws init), then
// atomicAdd + agent-scope spin + __threadfence both sides.
//
// ws (float offsets): SgTp 0 (36864) | Sg2Tp 36864 | XT 73728 (6144)
//  G 79872 (e1@0,e2@192,d1@6336,d2@12480; 12672) | Zx1 92544 | Zx2 98688
//  ZB1 104832 | ZB2 153984 (49152 ea) | ZA1 203136 | ZA2 301440 (98304 ea)
//  ZC1 399744 | ZC2 498048 (98304 ea) | B1 596352 | B2 645504 | B3 694656
//  BAR @ 743808 (unsigned cells, 128B apart)

#define NODES 192
#define NBLK 96
typedef float4 f4;

__device__ __forceinline__ void compute_c(const float* __restrict__ s, float c[3][3][3]) {
    const float s00 = s[0], s01 = s[1], s10 = s[2], s11 = s[3];
    #pragma unroll
    for (int k = 0; k < 3; ++k)
        #pragma unroll
        for (int d = 0; d < 3; ++d)
            #pragma unroll
            for (int p = 0; p < 3; ++p) c[k][d][p] = 0.f;
    c[0][0][0] = 1.f;
    c[1][0][0] = s00; c[1][0][1] = s01;
    c[1][1][0] = s10; c[1][1][1] = s11;
    c[2][0][0] = s00 * s00;       c[2][0][1] = 2.f * s00 * s01;               c[2][0][2] = s01 * s01;
    c[2][1][0] = 2.f * s00 * s10; c[2][1][1] = 2.f * (s00 * s11 + s01 * s10); c[2][1][2] = 2.f * s11 * s01;
    c[2][2][0] = s10 * s10;       c[2][2][1] = 2.f * s10 * s11;               c[2][2][2] = s11 * s11;
}

// Dual GEMV over half the n-range (h in {0,1}): partials -> ps[(mat*2+h)*IB+i][m].
template <int IB>
__device__ __forceinline__ void gemv2h(const f4* __restrict__ Ap, const f4* __restrict__ Bp,
                                       const float* __restrict__ xs, int h, int m,
                                       float* __restrict__ ps) {
    float a1[IB], a2[IB];
    #pragma unroll
    for (int i = 0; i < IB; ++i) { a1[i] = 0.f; a2[i] = 0.f; }
    const int jb = h * 24;
    f4 va[4], vb[4], na[4], nb[4];
    #pragma unroll
    for (int u = 0; u < 4; ++u) { va[u] = Ap[(jb + u) * NODES + m]; vb[u] = Bp[(jb + u) * NODES + m]; }
    #pragma unroll 1
    for (int g = 0; g < 6; ++g) {
        if (g < 5) {
            #pragma unroll
            for (int u = 0; u < 4; ++u) {
                na[u] = Ap[(jb + (g + 1) * 4 + u) * NODES + m];
                nb[u] = Bp[(jb + (g + 1) * 4 + u) * NODES + m];
            }
        }
        #pragma unroll
        for (int u = 0; u < 4; ++u) {
            const int n0 = 4 * (jb + g * 4 + u);
            #pragma unroll
            for (int i = 0; i < IB; ++i) {
                const float* xi = xs + i * NODES + n0;
                a1[i] += va[u].x * xi[0] + va[u].y * xi[1] + va[u].z * xi[2] + va[u].w * xi[3];
                a2[i] += vb[u].x * xi[0] + vb[u].y * xi[1] + vb[u].z * xi[2] + vb[u].w * xi[3];
            }
        }
        #pragma unroll
        for (int u = 0; u < 4; ++u) { va[u] = na[u]; vb[u] = nb[u]; }
    }
    #pragma unroll
    for (int i = 0; i < IB; ++i) {
        ps[((0 * 2 + h) * IB + i) * NODES + m] = a1[i];
        ps[((1 * 2 + h) * IB + i) * NODES + m] = a2[i];
    }
}

__device__ __forceinline__ void gridbar(unsigned* cell) {
    __syncthreads();
    if (threadIdx.x == 0) {
        __threadfence();                               // release (flush to coherence point)
        const unsigned got = atomicAdd(cell, 1u) + 1u;
        if (got != (unsigned)NBLK) {
            while (__hip_atomic_load(cell, __ATOMIC_RELAXED, __HIP_MEMORY_SCOPE_AGENT)
                   != (unsigned)NBLK)
                __builtin_amdgcn_s_sleep(8);
        }
    }
    __syncthreads();
    __threadfence();                                   // acquire (invalidate stale caches)
}

__global__ __launch_bounds__(384, 1) void mono_kernel(
        const float* __restrict__ X, const float* __restrict__ Sg, const float* __restrict__ s,
        const float* __restrict__ he1, const float* __restrict__ he2,
        const float* __restrict__ hd1, const float* __restrict__ hd2,
        float* __restrict__ out, float* __restrict__ ws) {
    const int b = blockIdx.x, t = threadIdx.x;
    const int h = t / NODES, m = t % NODES;

    float* SgTp  = ws;
    float* Sg2Tp = ws + 36864;
    float* XT    = ws + 73728;
    float* G     = ws + 79872;
    float* GE1 = G, *GE2 = G + 192, *GD1 = G + 6336, *GD2 = G + 12480;
    float* Zx1 = ws + 92544,  *Zx2 = ws + 98688;
    float* ZB1 = ws + 104832, *ZB2 = ws + 153984;
    float* ZA1 = ws + 203136, *ZA2 = ws + 301440;
    float* ZC1 = ws + 399744, *ZC2 = ws + 498048;
    float* B1  = ws + 596352, *B2 = ws + 645504, *B3 = ws + 694656;
    unsigned* bars = (unsigned*)(ws + 743808);
    const f4* Ap = (const f4*)SgTp;
    const f4* Bp = (const f4*)Sg2Tp;

    __shared__ __align__(16) float sm_a[1536];
    __shared__ __align__(16) float sm_v[768];
    __shared__ __align__(16) float sm_p[3072];

    // ---- ready-gate: make barrier cells valid regardless of ws initial contents ----
    if (t == 0) {
        if (b == 0) {
            for (int k = 0; k < 6; ++k) atomicExch(&bars[k * 32], 0u);
            __threadfence();
            atomicExch(&bars[6 * 32], 0x900DBEEFu);
        } else {
            while (__hip_atomic_load(&bars[6 * 32], __ATOMIC_RELAXED, __HIP_MEMORY_SCOPE_AGENT)
                   != 0x900DBEEFu)
                __builtin_amdgcn_s_sleep(8);
        }
    }
    __syncthreads();
    __threadfence();

    // ================= P0: XT, g tables, SgTp pack, Sg^2 =================
    {
        if (b < 16) {                                  // XT[t][n] = X[n][t]
            const int sid = b * 384 + t, tt2 = sid / NODES, n2 = sid % NODES;
            XT[tt2 * NODES + n2] = X[n2 * 32 + tt2];
        } else if (b == 16) {                          // g tables, padded to 12
            float c[3][3][3];
            compute_c(s, c);
            for (int w = t; w < 1056; w += 384) {
                const float* hh; int gbase, pl;
                if (w < 16)        { hh = he1; gbase = 0;     pl = w; }
                else if (w < 528)  { hh = he2; gbase = 192;   pl = w - 16; }
                else if (w < 1040) { hh = hd1; gbase = 6336;  pl = w - 528; }
                else               { hh = hd2; gbase = 12480; pl = w - 1040; }
                const float h0 = hh[pl * 3], h1 = hh[pl * 3 + 1], h2 = hh[pl * 3 + 2];
                float* gp = G + gbase + pl * 12;
                #pragma unroll
                for (int dp = 0; dp < 12; ++dp) {
                    float val = 0.f;
                    if (dp < 9) { const int d = dp / 3, p = dp % 3;
                                  val = h0 * c[0][d][p] + h1 * c[1][d][p] + h2 * c[2][d][p]; }
                    gp[dp] = val;
                }
            }
        }
        // all 96 blocks: rows mm = 2b, 2b+1 of SgTp pack + Sg^2
        const int mm = 2 * b + h, n = m;
        sm_a[h * NODES + n] = Sg[mm * NODES + n];
        __syncthreads();
        SgTp[(n >> 2) * 768 + mm * 4 + (n & 3)] = sm_a[h * NODES + n];
        float acc = 0.f;
        #pragma unroll 1
        for (int r0 = 0; r0 < NODES; r0 += 16) {
            float v[16];
            #pragma unroll
            for (int u = 0; u < 16; ++u) v[u] = Sg[(r0 + u) * NODES + n];
            #pragma unroll
            for (int u = 0; u < 16; ++u) acc += sm_a[h * NODES + r0 + u] * v[u];
        }
        Sg2Tp[(n >> 2) * 768 + mm * 4 + (n & 3)] = acc;
    }
    gridbar(&bars[0]);

    // ================= P1A: Zx = {Sg, Sg^2} x  (32 cols) =================
    if (b < 32) {
        if (h == 0) sm_a[m] = XT[b * NODES + m];
        __syncthreads();
        gemv2h<1>(Ap, Bp, sm_a, h, m, sm_p);
        __syncthreads();
        if (h == 0) {
            Zx1[b * NODES + m] = sm_p[m] + sm_p[NODES + m];
            Zx2[b * NODES + m] = sm_p[2 * NODES + m] + sm_p[3 * NODES + m];
        }
    }
    gridbar(&bars[1 * 32]);

    // ================= P1B: e1 conv+pool+relu -> B1; Z(L2) -> ZB =================
    if (b < 64) {
        const int q = b & 15, o0 = (b >> 4) * 4;
        if (t < 48) sm_a[t] = GE1[o0 * 12 + t];
        float x0[4], z1[4], z2[4];
        if (h == 0) {
            #pragma unroll
            for (int dl = 0; dl < 4; ++dl) {
                const int u = (2 * q + dl - 2) & 31;
                x0[dl] = XT[u * NODES + m];
                z1[dl] = Zx1[u * NODES + m];
                z2[dl] = Zx2[u * NODES + m];
            }
        }
        __syncthreads();
        if (h == 0) {
            float v[4];
            #pragma unroll
            for (int o = 0; o < 4; ++o) {
                const float* gr = &sm_a[o * 12];
                const f4 ga = *(const f4*)gr, gb = *(const f4*)(gr + 4), gc = *(const f4*)(gr + 8);
                float a0 = 0.f, a1 = 0.f;
                #pragma unroll
                for (int tt = 0; tt < 2; ++tt) {
                    const float a = ga.x * x0[tt + 2] + ga.y * z1[tt + 2] + ga.z * z2[tt + 2]
                                  + ga.w * x0[tt + 1] + gb.x * z1[tt + 1] + gb.y * z2[tt + 1]
                                  + gb.z * x0[tt]     + gb.w * z1[tt]     + gc.x * z2[tt];
                    if (tt == 0) a0 = a; else a1 = a;
                }
                v[o] = fmaxf(fmaxf(a0, a1), 0.f);
                sm_v[o * NODES + m] = v[o];
            }
            *(f4*)(B1 + (q * NODES + m) * 16 + o0) = make_float4(v[0], v[1], v[2], v[3]);
        }
        __syncthreads();
        gemv2h<4>(Ap, Bp, sm_v, h, m, sm_p);
        __syncthreads();
        if (h == 0) {
            f4 s1, s2;
            s1.x = sm_p[(0) * NODES + m] + sm_p[(4) * NODES + m];
            s1.y = sm_p[(1) * NODES + m] + sm_p[(5) * NODES + m];
            s1.z = sm_p[(2) * NODES + m] + sm_p[(6) * NODES + m];
            s1.w = sm_p[(3) * NODES + m] + sm_p[(7) * NODES + m];
            s2.x = sm_p[(8) * NODES + m] + sm_p[(12) * NODES + m];
            s2.y = sm_p[(9) * NODES + m] + sm_p[(13) * NODES + m];
            s2.z = sm_p[(10) * NODES + m] + sm_p[(14) * NODES + m];
            s2.w = sm_p[(11) * NODES + m] + sm_p[(15) * NODES + m];
            *(f4*)(ZB1 + (q * NODES + m) * 16 + o0) = s1;
            *(f4*)(ZB2 + (q * NODES + m) * 16 + o0) = s2;
        }
    }
    gridbar(&bars[2 * 32]);

    // ================= P2: e2 conv+pool+relu -> B2; Z(L3, zero-stuffed) -> ZA =================
    if (b < 64) {
        const int q = b & 7, oq = b >> 3, o0 = oq * 4;
        for (int idx = t; idx < 768; idx += 384) sm_a[idx] = GE2[oq * 768 + idx];
        __syncthreads();
        {
            const int i0 = h * 8;
            float pacc[2][4];
            #pragma unroll
            for (int tt = 0; tt < 2; ++tt)
                #pragma unroll
                for (int o = 0; o < 4; ++o) pacc[tt][o] = 0.f;
            float z[4][3][8];
            #pragma unroll
            for (int dl = 0; dl < 4; ++dl) {
                const int u = (2 * q + dl - 2) & 15;
                const int base = (u * NODES + m) * 16 + i0;
                *(f4*)&z[dl][0][0] = *(const f4*)(B1 + base);
                *(f4*)&z[dl][0][4] = *(const f4*)(B1 + base + 4);
                *(f4*)&z[dl][1][0] = *(const f4*)(ZB1 + base);
                *(f4*)&z[dl][1][4] = *(const f4*)(ZB1 + base + 4);
                *(f4*)&z[dl][2][0] = *(const f4*)(ZB2 + base);
                *(f4*)&z[dl][2][4] = *(const f4*)(ZB2 + base + 4);
            }
            #pragma unroll
            for (int o = 0; o < 4; ++o)
                #pragma unroll
                for (int ch = 0; ch < 8; ++ch) {
                    const float* gr = &sm_a[(o * 16 + i0 + ch) * 12];
                    const f4 ga = *(const f4*)gr, gb = *(const f4*)(gr + 4), gc = *(const f4*)(gr + 8);
                    #pragma unroll
                    for (int tt = 0; tt < 2; ++tt)
                        pacc[tt][o] += ga.x * z[tt + 2][0][ch] + ga.y * z[tt + 2][1][ch] + ga.z * z[tt + 2][2][ch]
                                     + ga.w * z[tt + 1][0][ch] + gb.x * z[tt + 1][1][ch] + gb.y * z[tt + 1][2][ch]
                                     + gb.z * z[tt][0][ch]     + gb.w * z[tt][1][ch]     + gc.x * z[tt][2][ch];
                }
            #pragma unroll
            for (int tt = 0; tt < 2; ++tt)
                #pragma unroll
                for (int o = 0; o < 4; ++o)
                    sm_p[((h * 2 + tt) * 4 + o) * NODES + m] = pacc[tt][o];
        }
        __syncthreads();
        if (h == 0) {
            float v[4];
            #pragma unroll
            for (int o = 0; o < 4; ++o) {
                const float r0 = sm_p[(o) * NODES + m] + sm_p[(8 + o) * NODES + m];
                const float r1 = sm_p[(4 + o) * NODES + m] + sm_p[(12 + o) * NODES + m];
                v[o] = fmaxf(fmaxf(r0, r1), 0.f);
                sm_v[o * NODES + m] = v[o];
            }
            *(f4*)(B2 + (q * NODES + m) * 32 + o0) = make_float4(v[0], v[1], v[2], v[3]);
        }
        __syncthreads();
        gemv2h<4>(Ap, Bp, sm_v, h, m, sm_p);
        __syncthreads();
        if (h == 0) {
            f4 s1, s2;
            s1.x = sm_p[(0) * NODES + m] + sm_p[(4) * NODES + m];
            s1.y = sm_p[(1) * NODES + m] + sm_p[(5) * NODES + m];
            s1.z = sm_p[(2) * NODES + m] + sm_p[(6) * NODES + m];
            s1.w = sm_p[(3) * NODES + m] + sm_p[(7) * NODES + m];
            s2.x = sm_p[(8) * NODES + m] + sm_p[(12) * NODES + m];
            s2.y = sm_p[(9) * NODES + m] + sm_p[(13) * NODES + m];
            s2.z = sm_p[(10) * NODES + m] + sm_p[(14) * NODES + m];
            s2.w = sm_p[(11) * NODES + m] + sm_p[(15) * NODES + m];
            const int t2 = 2 * q;
            *(f4*)(ZA1 + (t2 * NODES + m) * 32 + o0) = s1;
            *(f4*)(ZA2 + (t2 * NODES + m) * 32 + o0) = s2;
            const f4 zz = make_float4(0.f, 0.f, 0.f, 0.f);
            *(f4*)(ZA1 + ((t2 + 1) * NODES + m) * 32 + o0) = zz;
            *(f4*)(ZA2 + ((t2 + 1) * NODES + m) * 32 + o0) = zz;
        }
    }
    gridbar(&bars[3 * 32]);

    // ================= P3: d1 conv (relu(up(B2))) -> raw B3; Z(L4) -> ZC =================
    if (b < 64) {
        const int t16 = b & 15, oq = b >> 4, o0 = oq * 4;
        for (int idx = t; idx < 1536; idx += 384) sm_a[idx] = GD1[oq * 1536 + idx];
        __syncthreads();
        {
            float pacc[4];
            #pragma unroll
            for (int o = 0; o < 4; ++o) pacc[o] = 0.f;
            #pragma unroll 1
            for (int cc = 0; cc < 2; ++cc) {
                const int i0 = (2 * h + cc) * 8;
                float z[3][3][8];
                #pragma unroll
                for (int dl = 0; dl < 3; ++dl) {
                    const int u = (t16 + dl - 2) & 15;
                    const float msk = (u & 1) ? 0.f : 1.f;
                    const int sb = ((u >> 1) * NODES + m) * 32 + i0;
                    const int zb = (u * NODES + m) * 32 + i0;
                    const f4 p0 = *(const f4*)(B2 + sb), p1 = *(const f4*)(B2 + sb + 4);
                    *(f4*)&z[dl][1][0] = *(const f4*)(ZA1 + zb);
                    *(f4*)&z[dl][1][4] = *(const f4*)(ZA1 + zb + 4);
                    *(f4*)&z[dl][2][0] = *(const f4*)(ZA2 + zb);
                    *(f4*)&z[dl][2][4] = *(const f4*)(ZA2 + zb + 4);
                    z[dl][0][0] = fmaxf(p0.x, 0.f) * msk;  z[dl][0][1] = fmaxf(p0.y, 0.f) * msk;
                    z[dl][0][2] = fmaxf(p0.z, 0.f) * msk;  z[dl][0][3] = fmaxf(p0.w, 0.f) * msk;
                    z[dl][0][4] = fmaxf(p1.x, 0.f) * msk;  z[dl][0][5] = fmaxf(p1.y, 0.f) * msk;
                    z[dl][0][6] = fmaxf(p1.z, 0.f) * msk;  z[dl][0][7] = fmaxf(p1.w, 0.f) * msk;
                }
                #pragma unroll
                for (int o = 0; o < 4; ++o)
                    #pragma unroll
                    for (int ch = 0; ch < 8; ++ch) {
                        const float* gr = &sm_a[(o * 32 + i0 + ch) * 12];
                        const f4 ga = *(const f4*)gr, gb = *(const f4*)(gr + 4), gc = *(const f4*)(gr + 8);
                        pacc[o] += ga.x * z[2][0][ch] + ga.y * z[2][1][ch] + ga.z * z[2][2][ch]
                                 + ga.w * z[1][0][ch] + gb.x * z[1][1][ch] + gb.y * z[1][2][ch]
                                 + gb.z * z[0][0][ch] + gb.w * z[0][1][ch] + gc.x * z[0][2][ch];
                    }
            }
            #pragma unroll
            for (int o = 0; o < 4; ++o) sm_p[(h * 4 + o) * NODES + m] = pacc[o];
        }
        __syncthreads();
        if (h == 0) {
            float raw[4];
            #pragma unroll
            for (int o = 0; o < 4; ++o) {
                raw[o] = sm_p[(o) * NODES + m] + sm_p[(4 + o) * NODES + m];
                sm_v[o * NODES + m] = fmaxf(raw[o], 0.f);
            }
            *(f4*)(B3 + (t16 * NODES + m) * 16 + o0) = make_float4(raw[0], raw[1], raw[2], raw[3]);
        }
        __syncthreads();
        gemv2h<4>(Ap, Bp, sm_v, h, m, sm_p);
        __syncthreads();
        if (h == 0) {
            f4 s1, s2;
            s1.x = sm_p[(0) * NODES + m] + sm_p[(4) * NODES + m];
            s1.y = sm_p[(1) * NODES + m] + sm_p[(5) * NODES + m];
            s1.z = sm_p[(2) * NODES + m] + sm_p[(6) * NODES + m];
            s1.w = sm_p[(3) * NODES + m] + sm_p[(7) * NODES + m];
            s2.x = sm_p[(8) * NODES + m] + sm_p[(12) * NODES + m];
            s2.y = sm_p[(9) * NODES + m] + sm_p[(13) * NODES + m];
            s2.z = sm_p[(10) * NODES + m] + sm_p[(14) * NODES + m];
            s2.w = sm_p[(11) * NODES + m] + sm_p[(15) * NODES + m];
            const int t2 = 2 * t16;
            *(f4*)(ZC1 + (t2 * NODES + m) * 16 + o0) = s1;
            *(f4*)(ZC2 + (t2 * NODES + m) * 16 + o0) = s2;
            const f4 zz = make_float4(0.f, 0.f, 0.f, 0.f);
            *(f4*)(ZC1 + ((t2 + 1) * NODES + m) * 16 + o0) = zz;
            *(f4*)(ZC2 + ((t2 + 1) * NODES + m) * 16 + o0) = zz;
        }
    }
    gridbar(&bars[4 * 32]);

    // ================= P4: d2 final conv -> out[m*32+t] =================
    if (b < 32) {
        const int t32 = b;
        if (t < 192) sm_a[t] = GD2[t];
        __syncthreads();
        {
            const int i0 = h * 8;
            float acc = 0.f;
            float z[3][3][8];
            #pragma unroll
            for (int dl = 0; dl < 3; ++dl) {
                const int u = (t32 + dl - 2) & 31;
                const float msk = (u & 1) ? 0.f : 1.f;
                const int sb = ((u >> 1) * NODES + m) * 16 + i0;
                const int zb = (u * NODES + m) * 16 + i0;
                const f4 p0 = *(const f4*)(B3 + sb), p1 = *(const f4*)(B3 + sb + 4);
                *(f4*)&z[dl][1][0] = *(const f4*)(ZC1 + zb);
                *(f4*)&z[dl][1][4] = *(const f4*)(ZC1 + zb + 4);
                *(f4*)&z[dl][2][0] = *(const f4*)(ZC2 + zb);
                *(f4*)&z[dl][2][4] = *(const f4*)(ZC2 + zb + 4);
                z[dl][0][0] = fmaxf(p0.x, 0.f) * msk;  z[dl][0][1] = fmaxf(p0.y, 0.f) * msk;
                z[dl][0][2] = fmaxf(p0.z, 0.f) * msk;  z[dl][0][3] = fmaxf(p0.w, 0.f) * msk;
                z[dl][0][4] = fmaxf(p1.x, 0.f) * msk;  z[dl][0][5] = fmaxf(p1.y, 0.f) * msk;
                z[dl][0][6] = fmaxf(p1.z, 0.f) * msk;  z[dl][0][7] = fmaxf(p1.w, 0.f) * msk;
            }
            #pragma unroll
            for (int ch = 0; ch < 8; ++ch) {
                const float* gr = &sm_a[(i0 + ch) * 12];
                const f4 ga = *(const f4*)gr, gb = *(const f4*)(gr + 4), gc = *(const f4*)(gr + 8);
                acc += ga.x * z[2][0][ch] + ga.y * z[2][1][ch] + ga.z * z[2][2][ch]
                     + ga.w * z[1][0][ch] + gb.x * z[1][1][ch] + gb.y * z[1][2][ch]
                     + gb.z * z[0][0][ch] + gb.w * z[0][1][ch] + gc.x * z[0][2][ch];
            }
            sm_p[h * NODES + m] = acc;
        }
        __syncthreads();
        if (h == 0) out[m * 32 + t32] = sm_p[m] + sm_p[NODES + m];
    }
}

extern "C" void kernel_launch(void* const* d_in, const int* in_sizes, int n_in,
                              void* d_out, int out_size, void* d_ws, size_t ws_size,
                              hipStream_t stream) {
    (void)in_sizes; (void)n_in; (void)out_size; (void)ws_size;
    const float* X   = (const float*)d_in[0];
    const float* Sg  = (const float*)d_in[1];
    const float* s   = (const float*)d_in[2];
    const float* he1 = (const float*)d_in[3];
    const float* he2 = (const float*)d_in[4];
    const float* hd1 = (const float*)d_in[5];
    const float* hd2 = (const float*)d_in[6];
    mono_kernel<<<NBLK, 384, 0, stream>>>(X, Sg, s, he1, he2, hd1, hd2,
                                          (float*)d_out, (float*)d_ws);
}

// Round 7
// 139.563 us; speedup vs baseline: 1.3316x; 1.3316x over previous
//
#include <hip/hip_runtime.h>

// GTConv autoencoder on the product graph, MI355X.
// S = It (x) Ag + St (x) Bg, Ag = s00 I + s01 Sg, Bg = s10 I + s11 Sg (commute).
// => S^k x [t] = sum_{d,p<=k} c[k][d][p] * Sg^p x[t-d]  (cyclic in t).
// Conv: Y[t,m,o] = sum_i sum_{d,p} g[o,i,d,p] * Zp[t-d, i, m].
//
// Round-7: r5 structure (5 kernels, PASS) + REGISTER-LEAN bodies.
// Diagnosis r6: per-load serialization from VGPR spill (conv z[4][3][8]=96fl +
// gemv 4xf4 dbuf=128fl > 128 VGPR cap -> scratch). Fix: conv chunks of 4 ch
// (z[4][3][4]=48fl), unroll-1 chunk loops, gemv xs reads as f4. FP order
// identical to r5 -> bit-identical output expected.
//
// ws layout (float offsets):
//   SgTp 0 (36864) | Sg2Tp 36864 (36864) | XT 73728 (6144)
//   GE1 79872 (192) | GE2 80064 (6144) | GD1 86208 (6144) | GD2 92352 (192)
//   ZA1 92544 | ZA2 190848 | ZB1 289152 | ZB2 387456  (98304 each)
//   B1 485760 (49152) | B2 534912 (49152) | B3 584064 (49152)

#define NODES 192
typedef float4 f4;

__device__ __forceinline__ void compute_c(const float* __restrict__ s, float c[3][3][3]) {
    const float s00 = s[0], s01 = s[1], s10 = s[2], s11 = s[3];
    #pragma unroll
    for (int k = 0; k < 3; ++k)
        #pragma unroll
        for (int d = 0; d < 3; ++d)
            #pragma unroll
            for (int p = 0; p < 3; ++p) c[k][d][p] = 0.f;
    c[0][0][0] = 1.f;
    c[1][0][0] = s00; c[1][0][1] = s01;
    c[1][1][0] = s10; c[1][1][1] = s11;
    c[2][0][0] = s00 * s00;       c[2][0][1] = 2.f * s00 * s01;               c[2][0][2] = s01 * s01;
    c[2][1][0] = 2.f * s00 * s10; c[2][1][1] = 2.f * (s00 * s11 + s01 * s10); c[2][1][2] = 2.f * s11 * s01;
    c[2][2][0] = s10 * s10;       c[2][2][1] = 2.f * s10 * s11;               c[2][2][2] = s11 * s11;
}

// Dual GEMV: a1[i] = sum_n Sg[m,n] xs[i*192+n], a2[i] with Sg^2.
// Packed: Ap[j*192+m] = f4 {Sg[m][4j..4j+3]}. 1-deep prefetch, xs read as f4.
// Live regs: va/vb/na/nb = 64 fl + acc 2*IB + addr  (IB=4 -> ~80 fl, no spill).
template <int IB>
__device__ __forceinline__ void gemv2(const f4* __restrict__ Ap, const f4* __restrict__ Bp,
                                      const float* __restrict__ xs, int m,
                                      float* __restrict__ a1, float* __restrict__ a2) {
    #pragma unroll
    for (int i = 0; i < IB; ++i) { a1[i] = 0.f; a2[i] = 0.f; }
    f4 va[4], vb[4], na[4], nb[4];
    #pragma unroll
    for (int u = 0; u < 4; ++u) { va[u] = Ap[u * NODES + m]; vb[u] = Bp[u * NODES + m]; }
    #pragma unroll 1
    for (int jc = 0; jc < 12; ++jc) {
        if (jc < 11) {
            #pragma unroll
            for (int u = 0; u < 4; ++u) {
                na[u] = Ap[((jc + 1) * 4 + u) * NODES + m];
                nb[u] = Bp[((jc + 1) * 4 + u) * NODES + m];
            }
        }
        #pragma unroll
        for (int u = 0; u < 4; ++u) {
            #pragma unroll
            for (int i = 0; i < IB; ++i) {
                const f4 xv = ((const f4*)(xs + i * NODES))[jc * 4 + u];
                a1[i] += va[u].x * xv.x + va[u].y * xv.y + va[u].z * xv.z + va[u].w * xv.w;
                a2[i] += vb[u].x * xv.x + vb[u].y * xv.y + vb[u].z * xv.z + vb[u].w * xv.w;
            }
        }
        if (jc < 11) {
            #pragma unroll
            for (int u = 0; u < 4; ++u) { va[u] = na[u]; vb[u] = nb[u]; }
        }
    }
}

// prep: b<192 pack SgT; b<384 Sg^2 rows -> packed; b==384 g tables; b==385 XT.
__global__ __launch_bounds__(192) void prep_kernel(
        const float* __restrict__ X, const float* __restrict__ Sg, const float* __restrict__ s,
        const float* __restrict__ he1, const float* __restrict__ he2,
        const float* __restrict__ hd1, const float* __restrict__ hd2,
        float* __restrict__ ws) {
    const int b = blockIdx.x, tid = threadIdx.x;
    float* SgTp  = ws;
    float* Sg2Tp = ws + 36864;
    float* XT    = ws + 73728;
    float* g     = ws + 79872;
    if (b < 192) {
        const int mm = b, n = tid;
        SgTp[(n >> 2) * 768 + mm * 4 + (n & 3)] = Sg[mm * NODES + n];
    } else if (b < 384) {
        const int mm = b - 192, n = tid;
        __shared__ float row[NODES];
        row[tid] = Sg[mm * NODES + tid];
        __syncthreads();
        float acc = 0.f;
        #pragma unroll 1
        for (int r0 = 0; r0 < NODES; r0 += 16) {
            float v[16];
            #pragma unroll
            for (int u = 0; u < 16; ++u) v[u] = Sg[(r0 + u) * NODES + n];
            #pragma unroll
            for (int u = 0; u < 16; ++u) acc += row[r0 + u] * v[u];
        }
        Sg2Tp[(n >> 2) * 768 + mm * 4 + (n & 3)] = acc;
    } else if (b == 384) {
        float c[3][3][3];
        compute_c(s, c);
        for (int w = tid; w < 1056; w += 192) {
            const float* h; int gbase, pl;
            if (w < 16)        { h = he1; gbase = 0;     pl = w; }
            else if (w < 528)  { h = he2; gbase = 192;   pl = w - 16; }
            else if (w < 1040) { h = hd1; gbase = 6336;  pl = w - 528; }
            else               { h = hd2; gbase = 12480; pl = w - 1040; }
            const float h0 = h[pl * 3], h1 = h[pl * 3 + 1], h2 = h[pl * 3 + 2];
            float* gp = g + gbase + pl * 12;
            #pragma unroll
            for (int dp = 0; dp < 12; ++dp) {
                float val = 0.f;
                if (dp < 9) {
                    const int d = dp / 3, p = dp % 3;
                    val = h0 * c[0][d][p] + h1 * c[1][d][p] + h2 * c[2][d][p];
                }
                gp[dp] = val;
            }
        }
    } else {
        const int n = tid;
        const f4* xr = (const f4*)(X + n * 32);
        f4 vv[8];
        #pragma unroll
        for (int q = 0; q < 8; ++q) vv[q] = xr[q];
        #pragma unroll
        for (int q = 0; q < 8; ++q) {
            XT[(4 * q + 0) * NODES + n] = vv[q].x;
            XT[(4 * q + 1) * NODES + n] = vv[q].y;
            XT[(4 * q + 2) * NODES + n] = vv[q].z;
            XT[(4 * q + 3) * NODES + n] = vv[q].w;
        }
    }
}

// f1 (e1): 1->16, T=32, down+relu -> B1[16][192][16]; Z(L2) -> ZB[16][192][16].
__global__ __launch_bounds__(192) void f1_ker(
        const float* __restrict__ XT, const f4* __restrict__ Ap, const f4* __restrict__ Bp,
        const float* __restrict__ ge1, float* __restrict__ B1,
        float* __restrict__ Zb1, float* __restrict__ Zb2) {
    const int tq = blockIdx.x & 15, o0 = (blockIdx.x >> 4) * 4, m = threadIdx.x;
    __shared__ __align__(16) float xls[4 * NODES];
    __shared__ __align__(16) float vls[4 * NODES];
    __shared__ __align__(16) float gls[48];
    #pragma unroll
    for (int dl = 0; dl < 4; ++dl) {
        const int u = (2 * tq + dl - 2) & 31;
        xls[dl * NODES + m] = XT[u * NODES + m];
    }
    if (m < 48) gls[m] = ge1[o0 * 12 + m];
    __syncthreads();
    float z1[4], z2[4];
    gemv2<4>(Ap, Bp, xls, m, z1, z2);
    float x0[4];
    #pragma unroll
    for (int dl = 0; dl < 4; ++dl) x0[dl] = xls[dl * NODES + m];
    float acc[2][4];
    #pragma unroll
    for (int o = 0; o < 4; ++o) {
        const float* gr = &gls[o * 12];
        const f4 ga = *(const f4*)gr, gb = *(const f4*)(gr + 4), gc = *(const f4*)(gr + 8);
        #pragma unroll
        for (int tt = 0; tt < 2; ++tt) {
            acc[tt][o] = ga.x * x0[tt + 2] + ga.y * z1[tt + 2] + ga.z * z2[tt + 2]
                       + ga.w * x0[tt + 1] + gb.x * z1[tt + 1] + gb.y * z2[tt + 1]
                       + gb.z * x0[tt]     + gb.w * z1[tt]     + gc.x * z2[tt];
        }
    }
    float v[4];
    #pragma unroll
    for (int o = 0; o < 4; ++o) { v[o] = fmaxf(fmaxf(acc[0][o], acc[1][o]), 0.f); vls[o * NODES + m] = v[o]; }
    *(f4*)(B1 + (tq * NODES + m) * 16 + o0) = make_float4(v[0], v[1], v[2], v[3]);
    __syncthreads();
    float a1[4], a2[4];
    gemv2<4>(Ap, Bp, vls, m, a1, a2);
    *(f4*)(Zb1 + (tq * NODES + m) * 16 + o0) = make_float4(a1[0], a1[1], a1[2], a1[3]);
    *(f4*)(Zb2 + (tq * NODES + m) * 16 + o0) = make_float4(a2[0], a2[1], a2[2], a2[3]);
}

// f2 (e2): 16->32, T=16, down+relu -> B2[8][192][32]; Z(L3, zero-stuffed) -> ZA[16][192][32].
// Conv chunks of 4 channels (register-lean): z[4][3][4] = 48 floats.
__global__ __launch_bounds__(192) void f2_ker(
        const float* __restrict__ B1, const f4* __restrict__ Ap, const f4* __restrict__ Bp,
        const float* __restrict__ Zb1, const float* __restrict__ Zb2,
        const float* __restrict__ ge2, float* __restrict__ B2,
        float* __restrict__ Za1, float* __restrict__ Za2) {
    const int tq = blockIdx.x & 7, o0 = (blockIdx.x >> 3) * 4, m = threadIdx.x;
    __shared__ __align__(16) float gls[4 * 16 * 12];
    __shared__ __align__(16) float vls[4 * NODES];
    for (int idx = m; idx < 768; idx += NODES) gls[idx] = ge2[o0 * 16 * 12 + idx];
    __syncthreads();
    float acc[2][4];
    #pragma unroll
    for (int tt = 0; tt < 2; ++tt)
        #pragma unroll
        for (int o = 0; o < 4; ++o) acc[tt][o] = 0.f;
    #pragma unroll 1
    for (int ic = 0; ic < 4; ++ic) {
        float z[4][3][4];
        #pragma unroll
        for (int dl = 0; dl < 4; ++dl) {
            const int u = (2 * tq + dl - 2) & 15;
            const int base = (u * NODES + m) * 16 + ic * 4;
            *(f4*)&z[dl][0][0] = *(const f4*)(B1 + base);
            *(f4*)&z[dl][1][0] = *(const f4*)(Zb1 + base);
            *(f4*)&z[dl][2][0] = *(const f4*)(Zb2 + base);
        }
        #pragma unroll
        for (int o = 0; o < 4; ++o)
            #pragma unroll
            for (int ch = 0; ch < 4; ++ch) {
                const int i = ic * 4 + ch;
                const float* gr = &gls[(o * 16 + i) * 12];
                const f4 ga = *(const f4*)gr, gb = *(const f4*)(gr + 4), gc = *(const f4*)(gr + 8);
                #pragma unroll
                for (int tt = 0; tt < 2; ++tt) {
                    acc[tt][o] += ga.x * z[tt + 2][0][ch] + ga.y * z[tt + 2][1][ch] + ga.z * z[tt + 2][2][ch]
                                + ga.w * z[tt + 1][0][ch] + gb.x * z[tt + 1][1][ch] + gb.y * z[tt + 1][2][ch]
                                + gb.z * z[tt][0][ch]     + gb.w * z[tt][1][ch]     + gc.x * z[tt][2][ch];
                }
            }
    }
    float v[4];
    #pragma unroll
    for (int o = 0; o < 4; ++o) { v[o] = fmaxf(fmaxf(acc[0][o], acc[1][o]), 0.f); vls[o * NODES + m] = v[o]; }
    *(f4*)(B2 + (tq * NODES + m) * 32 + o0) = make_float4(v[0], v[1], v[2], v[3]);
    __syncthreads();
    float a1[4], a2[4];
    gemv2<4>(Ap, Bp, vls, m, a1, a2);
    const int t2 = 2 * tq;
    *(f4*)(Za1 + (t2 * NODES + m) * 32 + o0) = make_float4(a1[0], a1[1], a1[2], a1[3]);
    *(f4*)(Za2 + (t2 * NODES + m) * 32 + o0) = make_float4(a2[0], a2[1], a2[2], a2[3]);
    const f4 zz = make_float4(0.f, 0.f, 0.f, 0.f);
    *(f4*)(Za1 + ((t2 + 1) * NODES + m) * 32 + o0) = zz;
    *(f4*)(Za2 + ((t2 + 1) * NODES + m) * 32 + o0) = zz;
}

// f3 (d1): 32->16, T=16, input relu(up(B2)), raw -> B3; Z(L4, zero-stuffed) -> ZB.
// Conv chunks of 4 channels: z[3][3][4] = 36 floats.
__global__ __launch_bounds__(192) void f3_ker(
        const float* __restrict__ B2, const f4* __restrict__ Ap, const f4* __restrict__ Bp,
        const float* __restrict__ Za1, const float* __restrict__ Za2,
        const float* __restrict__ gd1, float* __restrict__ B3,
        float* __restrict__ Zb1, float* __restrict__ Zb2) {
    const int tq = blockIdx.x & 15, o0 = (blockIdx.x >> 4) * 4, m = threadIdx.x;
    __shared__ __align__(16) float gls[4 * 32 * 12];
    __shared__ __align__(16) float vls[4 * NODES];
    for (int idx = m; idx < 1536; idx += NODES) gls[idx] = gd1[o0 * 32 * 12 + idx];
    __syncthreads();
    float acc[4];
    #pragma unroll
    for (int o = 0; o < 4; ++o) acc[o] = 0.f;
    #pragma unroll 1
    for (int ic = 0; ic < 8; ++ic) {
        float z[3][3][4];
        #pragma unroll
        for (int dl = 0; dl < 3; ++dl) {
            const int u = (tq + dl - 2) & 15;
            const float msk = (u & 1) ? 0.f : 1.f;
            const int sb = ((u >> 1) * NODES + m) * 32 + ic * 4;
            const int zb = (u * NODES + m) * 32 + ic * 4;
            const f4 p0 = *(const f4*)(B2 + sb);
            *(f4*)&z[dl][1][0] = *(const f4*)(Za1 + zb);
            *(f4*)&z[dl][2][0] = *(const f4*)(Za2 + zb);
            z[dl][0][0] = fmaxf(p0.x, 0.f) * msk;  z[dl][0][1] = fmaxf(p0.y, 0.f) * msk;
            z[dl][0][2] = fmaxf(p0.z, 0.f) * msk;  z[dl][0][3] = fmaxf(p0.w, 0.f) * msk;
        }
        #pragma unroll
        for (int o = 0; o < 4; ++o)
            #pragma unroll
            for (int ch = 0; ch < 4; ++ch) {
                const int i = ic * 4 + ch;
                const float* gr = &gls[(o * 32 + i) * 12];
                const f4 ga = *(const f4*)gr, gb = *(const f4*)(gr + 4), gc = *(const f4*)(gr + 8);
                acc[o] += ga.x * z[2][0][ch] + ga.y * z[2][1][ch] + ga.z * z[2][2][ch]
                        + ga.w * z[1][0][ch] + gb.x * z[1][1][ch] + gb.y * z[1][2][ch]
                        + gb.z * z[0][0][ch] + gb.w * z[0][1][ch] + gc.x * z[0][2][ch];
            }
    }
    float v[4];
    #pragma unroll
    for (int o = 0; o < 4; ++o) { v[o] = fmaxf(acc[o], 0.f); vls[o * NODES + m] = v[o]; }
    *(f4*)(B3 + (tq * NODES + m) * 16 + o0) = make_float4(acc[0], acc[1], acc[2], acc[3]);  // raw
    __syncthreads();
    float a1[4], a2[4];
    gemv2<4>(Ap, Bp, vls, m, a1, a2);
    const int t2 = 2 * tq;
    *(f4*)(Zb1 + (t2 * NODES + m) * 16 + o0) = make_float4(a1[0], a1[1], a1[2], a1[3]);
    *(f4*)(Zb2 + (t2 * NODES + m) * 16 + o0) = make_float4(a2[0], a2[1], a2[2], a2[3]);
    const f4 zz = make_float4(0.f, 0.f, 0.f, 0.f);
    *(f4*)(Zb1 + ((t2 + 1) * NODES + m) * 16 + o0) = zz;
    *(f4*)(Zb2 + ((t2 + 1) * NODES + m) * 16 + o0) = zz;
}

// cker4 (d2): 16->1, T=32, input relu(up(B3)), out[m*32+t]. Chunks of 4 ch.
__global__ __launch_bounds__(192) void cker4(
        const float* __restrict__ B3,
        const float* __restrict__ Zb1, const float* __restrict__ Zb2,
        const float* __restrict__ gd2, float* __restrict__ out) {
    const int t = blockIdx.x, m = threadIdx.x;
    __shared__ __align__(16) float gls[16 * 12];
    for (int idx = m; idx < 192; idx += NODES) gls[idx] = gd2[idx];
    __syncthreads();
    float acc = 0.f;
    #pragma unroll 1
    for (int ic = 0; ic < 4; ++ic) {
        float z[3][3][4];
        #pragma unroll
        for (int dl = 0; dl < 3; ++dl) {
            const int u = (t + dl - 2) & 31;
            const float msk = (u & 1) ? 0.f : 1.f;
            const int sb = ((u >> 1) * NODES + m) * 16 + ic * 4;
            const int zb = (u * NODES + m) * 16 + ic * 4;
            const f4 p0 = *(const f4*)(B3 + sb);
            *(f4*)&z[dl][1][0] = *(const f4*)(Zb1 + zb);
            *(f4*)&z[dl][2][0] = *(const f4*)(Zb2 + zb);
            z[dl][0][0] = fmaxf(p0.x, 0.f) * msk;  z[dl][0][1] = fmaxf(p0.y, 0.f) * msk;
            z[dl][0][2] = fmaxf(p0.z, 0.f) * msk;  z[dl][0][3] = fmaxf(p0.w, 0.f) * msk;
        }
        #pragma unroll
        for (int ch = 0; ch < 4; ++ch) {
            const int i = ic * 4 + ch;
            const float* gr = &gls[i * 12];
            const f4 ga = *(const f4*)gr, gb = *(const f4*)(gr + 4), gc = *(const f4*)(gr + 8);
            acc += ga.x * z[2][0][ch] + ga.y * z[2][1][ch] + ga.z * z[2][2][ch]
                 + ga.w * z[1][0][ch] + gb.x * z[1][1][ch] + gb.y * z[1][2][ch]
                 + gb.z * z[0][0][ch] + gb.w * z[0][1][ch] + gc.x * z[0][2][ch];
        }
    }
    out[m * 32 + t] = acc;
}

extern "C" void kernel_launch(void* const* d_in, const int* in_sizes, int n_in,
                              void* d_out, int out_size, void* d_ws, size_t ws_size,
                              hipStream_t stream) {
    (void)in_sizes; (void)n_in; (void)out_size; (void)ws_size;
    const float* X   = (const float*)d_in[0];
    const float* Sg  = (const float*)d_in[1];
    const float* s   = (const float*)d_in[2];
    const float* he1 = (const float*)d_in[3];
    const float* he2 = (const float*)d_in[4];
    const float* hd1 = (const float*)d_in[5];
    const float* hd2 = (const float*)d_in[6];
    float* out = (float*)d_out;
    float* ws  = (float*)d_ws;

    const f4* Ap = (const f4*)(ws);
    const f4* Bp = (const f4*)(ws + 36864);
    float* XT  = ws + 73728;
    float* GE1 = ws + 79872;
    float* GE2 = ws + 80064;
    float* GD1 = ws + 86208;
    float* GD2 = ws + 92352;
    float* ZA1 = ws + 92544;
    float* ZA2 = ws + 190848;
    float* ZB1 = ws + 289152;
    float* ZB2 = ws + 387456;
    float* B1  = ws + 485760;
    float* B2  = ws + 534912;
    float* B3  = ws + 584064;

    prep_kernel<<<386, 192, 0, stream>>>(X, Sg, s, he1, he2, hd1, hd2, ws);
    f1_ker<<<64, 192, 0, stream>>>(XT, Ap, Bp, GE1, B1, ZB1, ZB2);
    f2_ker<<<64, 192, 0, stream>>>(B1, Ap, Bp, ZB1, ZB2, GE2, B2, ZA1, ZA2);
    f3_ker<<<64, 192, 0, stream>>>(B2, Ap, Bp, ZA1, ZA2, GD1, B3, ZB1, ZB2);
    cker4<<<32, 192, 0, stream>>>(B3, ZB1, ZB2, GD2, out);
}

// Round 8
// 103.331 us; speedup vs baseline: 1.7986x; 1.3506x over previous
//
#include <hip/hip_runtime.h>

// GTConv autoencoder, MI355X. Round-8: latency-chain minimization.
// Math (PASS r2/r3/r5/r6/r7): S^k x[t] = sum_{d,p} c[k][d][p] Sg^p x[t-d];
// Y[t,m,o] = sum_i sum_{d,p} g[o,i,d,p] Zp[t-d,i,m]; Z1=Sg x, Z2=Sg^2 x.
// Diagnosis r7: GEMV 1-deep prefetch = 12 serial round-trips (in-order waves,
// ~500-900cy each, 1-2 waves/SIMD -> fully exposed). Fix: split dots 4-way
// across threads so EVERY kernel issues all loads in one batch (1-2 RTs),
// LDS-reduce partials. 9 small dispatches, layouts all [t][i][m] (m fastest).
//
// ws (float offsets): SgTp 0 (36864) | Sg2Tp 36864 | XT 73728 (6144)
//  G 79872: GE1@0(192) GE2@192(6144) GD1@6336(6144) GD2@12480(192)
//  Zx1 92544 (6144) | Zx2 98688 | ZB1 104832 (49152) | ZB2 153984
//  ZA1 203136 (98304) | ZA2 301440 | ZC1 399744 (98304) | ZC2 498048
//  B1 596352 (49152) | B2 645504 (49152) | B3 694656 (49152)

#define NODES 192
typedef float4 f4;

__device__ __forceinline__ void compute_c(const float* __restrict__ s, float c[3][3][3]) {
    const float s00 = s[0], s01 = s[1], s10 = s[2], s11 = s[3];
    #pragma unroll
    for (int k = 0; k < 3; ++k)
        #pragma unroll
        for (int d = 0; d < 3; ++d)
            #pragma unroll
            for (int p = 0; p < 3; ++p) c[k][d][p] = 0.f;
    c[0][0][0] = 1.f;
    c[1][0][0] = s00; c[1][0][1] = s01;
    c[1][1][0] = s10; c[1][1][1] = s11;
    c[2][0][0] = s00 * s00;       c[2][0][1] = 2.f * s00 * s01;               c[2][0][2] = s01 * s01;
    c[2][1][0] = 2.f * s00 * s10; c[2][1][1] = 2.f * (s00 * s11 + s01 * s10); c[2][1][2] = 2.f * s11 * s01;
    c[2][2][0] = s10 * s10;       c[2][2][1] = 2.f * s10 * s11;               c[2][2][2] = s11 * s11;
}

// ---------- prep: blocks 0..191 row-m {SgTp pack + Sg^2 row}; 192 g; 193 XT ----------
__global__ __launch_bounds__(768) void prep_kernel(
        const float* __restrict__ X, const float* __restrict__ Sg, const float* __restrict__ s,
        const float* __restrict__ he1, const float* __restrict__ he2,
        const float* __restrict__ hd1, const float* __restrict__ hd2,
        float* __restrict__ ws) {
    const int b = blockIdx.x, tid = threadIdx.x;
    float* SgTp  = ws;
    float* Sg2Tp = ws + 36864;
    float* XT    = ws + 73728;
    float* G     = ws + 79872;
    if (b < 192) {
        __shared__ float row[NODES];
        __shared__ float ps[4 * NODES];
        if (tid < NODES) {
            const float v = Sg[b * NODES + tid];
            row[tid] = v;
            SgTp[(tid >> 2) * 768 + b * 4 + (tid & 3)] = v;   // pack SgT
        }
        __syncthreads();
        const int n = tid % NODES, q = tid / NODES;
        float v[48];
        #pragma unroll
        for (int rr = 0; rr < 48; ++rr) v[rr] = Sg[(48 * q + rr) * NODES + n];  // 1 batched RT
        float acc = 0.f;
        #pragma unroll
        for (int rr = 0; rr < 48; ++rr) acc += row[48 * q + rr] * v[rr];
        ps[q * NODES + n] = acc;
        __syncthreads();
        if (q == 0) {
            const float s2 = ps[n] + ps[NODES + n] + ps[2 * NODES + n] + ps[3 * NODES + n];
            Sg2Tp[(n >> 2) * 768 + b * 4 + (n & 3)] = s2;
        }
    } else if (b == 192) {
        float c[3][3][3];
        compute_c(s, c);
        for (int w = tid; w < 1056; w += 768) {
            const float* h; int gbase, pl;
            if (w < 16)        { h = he1; gbase = 0;     pl = w; }
            else if (w < 528)  { h = he2; gbase = 192;   pl = w - 16; }
            else if (w < 1040) { h = hd1; gbase = 6336;  pl = w - 528; }
            else               { h = hd2; gbase = 12480; pl = w - 1040; }
            const float h0 = h[pl * 3], h1 = h[pl * 3 + 1], h2 = h[pl * 3 + 2];
            float* gp = G + gbase + pl * 12;
            #pragma unroll
            for (int dp = 0; dp < 12; ++dp) {
                float val = 0.f;
                if (dp < 9) { const int d = dp / 3, p = dp % 3;
                              val = h0 * c[0][d][p] + h1 * c[1][d][p] + h2 * c[2][d][p]; }
                gp[dp] = val;
            }
        }
    } else {
        if (tid < NODES) {
            const f4* xr = (const f4*)(X + tid * 32);
            f4 vv[8];
            #pragma unroll
            for (int qq = 0; qq < 8; ++qq) vv[qq] = xr[qq];
            #pragma unroll
            for (int qq = 0; qq < 8; ++qq) {
                XT[(4 * qq + 0) * NODES + tid] = vv[qq].x;
                XT[(4 * qq + 1) * NODES + tid] = vv[qq].y;
                XT[(4 * qq + 2) * NODES + tid] = vv[qq].z;
                XT[(4 * qq + 3) * NODES + tid] = vv[qq].w;
            }
        }
    }
}

// ---------- zkern: Z1/Z2 for one (t,i) column. 768 thr = (m, n-quarter q). ----------
// INMODE 0: src[t*192+n] (XT/Zx layout, CIN==1). 1: src[(t*CIN+i)*192+n]. 2: same + relu.
// UP: write at t2=2t and zero t2+1 rows.
template <int CIN, int TREAL, int INMODE, int UP>
__global__ __launch_bounds__(768) void zkern(
        const float* __restrict__ src, const f4* __restrict__ Ap, const f4* __restrict__ Bp,
        float* __restrict__ Z1, float* __restrict__ Z2) {
    const int t = blockIdx.x % TREAL, i = blockIdx.x / TREAL;
    const int m = threadIdx.x % NODES, q = threadIdx.x / NODES;
    __shared__ __align__(16) float xs[NODES];
    __shared__ float ps[8 * NODES];
    if (threadIdx.x < NODES) {
        float v = (INMODE == 0) ? src[t * NODES + threadIdx.x]
                                : src[(t * CIN + i) * NODES + threadIdx.x];
        if (INMODE == 2) v = fmaxf(v, 0.f);
        xs[threadIdx.x] = v;
    }
    __syncthreads();
    f4 va[12], vb[12];
    #pragma unroll
    for (int jj = 0; jj < 12; ++jj) va[jj] = Ap[(12 * q + jj) * NODES + m];   // 24 loads,
    #pragma unroll
    for (int jj = 0; jj < 12; ++jj) vb[jj] = Bp[(12 * q + jj) * NODES + m];   // one batch
    const f4* xv = (const f4*)xs;
    float a1 = 0.f, a2 = 0.f;
    #pragma unroll
    for (int jj = 0; jj < 12; ++jj) {
        const f4 x = xv[12 * q + jj];
        a1 += va[jj].x * x.x + va[jj].y * x.y + va[jj].z * x.z + va[jj].w * x.w;
        a2 += vb[jj].x * x.x + vb[jj].y * x.y + vb[jj].z * x.z + vb[jj].w * x.w;
    }
    ps[q * NODES + m] = a1;
    ps[(4 + q) * NODES + m] = a2;
    __syncthreads();
    const int t2 = UP ? 2 * t : t;
    const int base = (t2 * CIN + i) * NODES + m;
    if (q == 0)
        Z1[base] = ps[m] + ps[NODES + m] + ps[2 * NODES + m] + ps[3 * NODES + m];
    else if (q == 1)
        Z2[base] = ps[4 * NODES + m] + ps[5 * NODES + m] + ps[6 * NODES + m] + ps[7 * NODES + m];
    else if (UP && q == 2)
        Z1[((t2 + 1) * CIN + i) * NODES + m] = 0.f;
    else if (UP && q == 3)
        Z2[((t2 + 1) * CIN + i) * NODES + m] = 0.f;
}

// ---------- f1 (e1): 1->16, T=32, pool+relu -> B1[16][16][192] ----------
__global__ __launch_bounds__(768) void f1_ker(
        const float* __restrict__ XT, const float* __restrict__ Zx1, const float* __restrict__ Zx2,
        const float* __restrict__ ge1, float* __restrict__ B1) {
    const int q = blockIdx.x;
    const int m = threadIdx.x % NODES, og = threadIdx.x / NODES;
    __shared__ __align__(16) float gls[192];
    if (threadIdx.x < 192) gls[threadIdx.x] = ge1[threadIdx.x];
    float x0[4], z1[4], z2[4];
    #pragma unroll
    for (int dl = 0; dl < 4; ++dl) {
        const int u = (2 * q + dl - 2) & 31;
        x0[dl] = XT[u * NODES + m];
        z1[dl] = Zx1[u * NODES + m];
        z2[dl] = Zx2[u * NODES + m];
    }
    __syncthreads();
    #pragma unroll
    for (int oi = 0; oi < 4; ++oi) {
        const int o = og * 4 + oi;
        const float* gr = &gls[o * 12];
        const f4 ga = *(const f4*)gr, gb = *(const f4*)(gr + 4), gc = *(const f4*)(gr + 8);
        float a[2];
        #pragma unroll
        for (int tt = 0; tt < 2; ++tt)
            a[tt] = ga.x * x0[tt + 2] + ga.y * z1[tt + 2] + ga.z * z2[tt + 2]
                  + ga.w * x0[tt + 1] + gb.x * z1[tt + 1] + gb.y * z2[tt + 1]
                  + gb.z * x0[tt]     + gb.w * z1[tt]     + gc.x * z2[tt];
        B1[(q * 16 + o) * NODES + m] = fmaxf(fmaxf(a[0], a[1]), 0.f);
    }
}

// ---------- f2 (e2): 16->32, T=16, pool+relu -> B2[8][32][192] ----------
// block = (q 0..7, oo 0..3 of 8 o's); thread = (m, cq of 4 i's).
__global__ __launch_bounds__(768) void f2_ker(
        const float* __restrict__ B1,
        const float* __restrict__ ZB1, const float* __restrict__ ZB2,
        const float* __restrict__ ge2, float* __restrict__ B2) {
    const int q = blockIdx.x & 7, oo = blockIdx.x >> 3;
    const int m = threadIdx.x % NODES, cq = threadIdx.x / NODES;
    __shared__ __align__(16) float gls[1536];
    __shared__ float ps[4 * 2 * 8 * NODES];
    for (int idx = threadIdx.x; idx < 1536; idx += 768) gls[idx] = ge2[oo * 1536 + idx];
    const int i0 = cq * 4;
    float xv[4][4], z1v[4][4], z2v[4][4];
    #pragma unroll
    for (int dl = 0; dl < 4; ++dl) {
        const int u = (2 * q + dl - 2) & 15;
        const int base = (u * 16 + i0) * NODES + m;
        #pragma unroll
        for (int ii = 0; ii < 4; ++ii) xv[dl][ii]  = B1[base + ii * NODES];
        #pragma unroll
        for (int ii = 0; ii < 4; ++ii) z1v[dl][ii] = ZB1[base + ii * NODES];
        #pragma unroll
        for (int ii = 0; ii < 4; ++ii) z2v[dl][ii] = ZB2[base + ii * NODES];
    }
    __syncthreads();
    #pragma unroll
    for (int o = 0; o < 8; ++o) {
        float a[2] = {0.f, 0.f};
        #pragma unroll
        for (int ii = 0; ii < 4; ++ii) {
            const float* gr = &gls[(o * 16 + i0 + ii) * 12];
            const f4 ga = *(const f4*)gr, gb = *(const f4*)(gr + 4), gc = *(const f4*)(gr + 8);
            #pragma unroll
            for (int tt = 0; tt < 2; ++tt)
                a[tt] += ga.x * xv[tt + 2][ii] + ga.y * z1v[tt + 2][ii] + ga.z * z2v[tt + 2][ii]
                       + ga.w * xv[tt + 1][ii] + gb.x * z1v[tt + 1][ii] + gb.y * z2v[tt + 1][ii]
                       + gb.z * xv[tt][ii]     + gb.w * z1v[tt][ii]     + gc.x * z2v[tt][ii];
        }
        ps[((cq * 2 + 0) * 8 + o) * NODES + m] = a[0];
        ps[((cq * 2 + 1) * 8 + o) * NODES + m] = a[1];
    }
    __syncthreads();
    #pragma unroll
    for (int oi = 0; oi < 2; ++oi) {
        const int o = cq * 2 + oi;
        float r0 = 0.f, r1 = 0.f;
        #pragma unroll
        for (int c = 0; c < 4; ++c) {
            r0 += ps[((c * 2 + 0) * 8 + o) * NODES + m];
            r1 += ps[((c * 2 + 1) * 8 + o) * NODES + m];
        }
        B2[(q * 32 + oo * 8 + o) * NODES + m] = fmaxf(fmaxf(r0, r1), 0.f);
    }
}

// ---------- f3 (d1): 32->16, T=16, in relu(up(B2)) via mask, raw -> B3[16][16][192] ----------
// block = (t 0..15, og 0..3 of 4 o's); thread = (m, cq of 8 i's in 2 chunks).
__global__ __launch_bounds__(768) void f3_ker(
        const float* __restrict__ B2,
        const float* __restrict__ ZA1, const float* __restrict__ ZA2,
        const float* __restrict__ gd1, float* __restrict__ B3) {
    const int t = blockIdx.x & 15, og = blockIdx.x >> 4;
    const int m = threadIdx.x % NODES, cq = threadIdx.x / NODES;
    __shared__ __align__(16) float gls[1536];
    __shared__ float ps[4 * 4 * NODES];
    for (int idx = threadIdx.x; idx < 1536; idx += 768) gls[idx] = gd1[og * 1536 + idx];
    float acc[4] = {0.f, 0.f, 0.f, 0.f};
    #pragma unroll
    for (int cc = 0; cc < 2; ++cc) {
        const int i0 = cq * 8 + cc * 4;
        float xv[3][4], z1v[3][4], z2v[3][4];
        #pragma unroll
        for (int dl = 0; dl < 3; ++dl) {
            const int u = (t + dl - 2) & 15;
            const float msk = (u & 1) ? 0.f : 1.f;
            const int sb = ((u >> 1) * 32 + i0) * NODES + m;
            const int zb = (u * 32 + i0) * NODES + m;
            #pragma unroll
            for (int ii = 0; ii < 4; ++ii) xv[dl][ii]  = B2[sb + ii * NODES] * msk;  // B2 >= 0
            #pragma unroll
            for (int ii = 0; ii < 4; ++ii) z1v[dl][ii] = ZA1[zb + ii * NODES];
            #pragma unroll
            for (int ii = 0; ii < 4; ++ii) z2v[dl][ii] = ZA2[zb + ii * NODES];
        }
        if (cc == 0) __syncthreads();   // gls ready before first use
        #pragma unroll
        for (int o = 0; o < 4; ++o)
            #pragma unroll
            for (int ii = 0; ii < 4; ++ii) {
                const float* gr = &gls[(o * 32 + i0 + ii) * 12];
                const f4 ga = *(const f4*)gr, gb = *(const f4*)(gr + 4), gc = *(const f4*)(gr + 8);
                acc[o] += ga.x * xv[2][ii] + ga.y * z1v[2][ii] + ga.z * z2v[2][ii]
                        + ga.w * xv[1][ii] + gb.x * z1v[1][ii] + gb.y * z2v[1][ii]
                        + gb.z * xv[0][ii] + gb.w * z1v[0][ii] + gc.x * z2v[0][ii];
            }
    }
    #pragma unroll
    for (int o = 0; o < 4; ++o) ps[(cq * 4 + o) * NODES + m] = acc[o];
    __syncthreads();
    {
        const int o = cq;   // 4 o's, 4 cq's: 1:1
        const float raw = ps[(0 * 4 + o) * NODES + m] + ps[(1 * 4 + o) * NODES + m]
                        + ps[(2 * 4 + o) * NODES + m] + ps[(3 * 4 + o) * NODES + m];
        B3[(t * 16 + og * 4 + o) * NODES + m] = raw;   // raw (relu applied by readers)
    }
}

// ---------- f4 (d2): 16->1, T=32, in relu(up(B3)) via mask+relu -> out[m*32+t] ----------
__global__ __launch_bounds__(768) void f4_ker(
        const float* __restrict__ B3,
        const float* __restrict__ ZC1, const float* __restrict__ ZC2,
        const float* __restrict__ gd2, float* __restrict__ out) {
    const int t = blockIdx.x;
    const int m = threadIdx.x % NODES, cq = threadIdx.x / NODES;
    __shared__ __align__(16) float gls[192];
    __shared__ float ps[4 * NODES];
    if (threadIdx.x < 192) gls[threadIdx.x] = gd2[threadIdx.x];
    const int i0 = cq * 4;
    float xv[3][4], z1v[3][4], z2v[3][4];
    #pragma unroll
    for (int dl = 0; dl < 3; ++dl) {
        const int u = (t + dl - 2) & 31;
        const float msk = (u & 1) ? 0.f : 1.f;
        const int sb = ((u >> 1) * 16 + i0) * NODES + m;
        const int zb = (u * 16 + i0) * NODES + m;
        #pragma unroll
        for (int ii = 0; ii < 4; ++ii) xv[dl][ii]  = fmaxf(B3[sb + ii * NODES], 0.f) * msk;
        #pragma unroll
        for (int ii = 0; ii < 4; ++ii) z1v[dl][ii] = ZC1[zb + ii * NODES];
        #pragma unroll
        for (int ii = 0; ii < 4; ++ii) z2v[dl][ii] = ZC2[zb + ii * NODES];
    }
    __syncthreads();
    float acc = 0.f;
    #pragma unroll
    for (int ii = 0; ii < 4; ++ii) {
        const float* gr = &gls[(i0 + ii) * 12];
        const f4 ga = *(const f4*)gr, gb = *(const f4*)(gr + 4), gc = *(const f4*)(gr + 8);
        acc += ga.x * xv[2][ii] + ga.y * z1v[2][ii] + ga.z * z2v[2][ii]
             + ga.w * xv[1][ii] + gb.x * z1v[1][ii] + gb.y * z2v[1][ii]
             + gb.z * xv[0][ii] + gb.w * z1v[0][ii] + gc.x * z2v[0][ii];
    }
    ps[cq * NODES + m] = acc;
    __syncthreads();
    if (cq == 0)
        out[m * 32 + t] = ps[m] + ps[NODES + m] + ps[2 * NODES + m] + ps[3 * NODES + m];
}

extern "C" void kernel_launch(void* const* d_in, const int* in_sizes, int n_in,
                              void* d_out, int out_size, void* d_ws, size_t ws_size,
                              hipStream_t stream) {
    (void)in_sizes; (void)n_in; (void)out_size; (void)ws_size;
    const float* X   = (const float*)d_in[0];
    const float* Sg  = (const float*)d_in[1];
    const float* s   = (const float*)d_in[2];
    const float* he1 = (const float*)d_in[3];
    const float* he2 = (const float*)d_in[4];
    const float* hd1 = (const float*)d_in[5];
    const float* hd2 = (const float*)d_in[6];
    float* out = (float*)d_out;
    float* ws  = (float*)d_ws;

    const f4* Ap = (const f4*)(ws);
    const f4* Bp = (const f4*)(ws + 36864);
    float* XT  = ws + 73728;
    float* GE1 = ws + 79872;
    float* GE2 = ws + 80064;
    float* GD1 = ws + 86208;
    float* GD2 = ws + 92352;
    float* Zx1 = ws + 92544;
    float* Zx2 = ws + 98688;
    float* ZB1 = ws + 104832;
    float* ZB2 = ws + 153984;
    float* ZA1 = ws + 203136;
    float* ZA2 = ws + 301440;
    float* ZC1 = ws + 399744;
    float* ZC2 = ws + 498048;
    float* B1  = ws + 596352;
    float* B2  = ws + 645504;
    float* B3  = ws + 694656;

    prep_kernel<<<194, 768, 0, stream>>>(X, Sg, s, he1, he2, hd1, hd2, ws);
    zkern<1, 32, 0, 0><<<32, 768, 0, stream>>>(XT, Ap, Bp, Zx1, Zx2);       // Z(x)
    f1_ker<<<16, 768, 0, stream>>>(XT, Zx1, Zx2, GE1, B1);                  // e1 -> B1
    zkern<16, 16, 1, 0><<<256, 768, 0, stream>>>(B1, Ap, Bp, ZB1, ZB2);     // Z(L2)
    f2_ker<<<32, 768, 0, stream>>>(B1, ZB1, ZB2, GE2, B2);                  // e2 -> B2
    zkern<32, 8, 1, 1><<<256, 768, 0, stream>>>(B2, Ap, Bp, ZA1, ZA2);      // Z(L3, up)
    f3_ker<<<64, 768, 0, stream>>>(B2, ZA1, ZA2, GD1, B3);                  // d1 -> B3 raw
    zkern<16, 16, 2, 1><<<256, 768, 0, stream>>>(B3, Ap, Bp, ZC1, ZC2);     // Z(L4, up+relu)
    f4_ker<<<32, 768, 0, stream>>>(B3, ZC1, ZC2, GD2, out);                 // d2 -> out
}